// Round 2
// baseline (529.453 us; speedup 1.0000x reference)
//
#include <hip/hip_runtime.h>

// MPS classifier: logits[b,o] = (v/||v||)·cls[o] + log||v||,
//   v = head0(b) · M_1(b) · ... · M_783(b),  M_n = A_n + x[b,n]*(B_n - A_n).
// Chain is associative and all normalizations telescope, so we:
//   K0: repack cores -> per-site [A_row | Delta_row] (saves B-A per lane per site)
//   K1: each lane computes the full 10x10 product of one (sample, chunk) of
//       ~13 consecutive sites, entirely in registers (no cross-lane traffic),
//       Frobenius-renormalized once per chunk.  2048 samples x 61 chunks
//       -> 1952 waves (vs 512 before), ~2 waves/SIMD at ~240 VGPR.
//   K2: per-sample sequential combine head·P_0·P_1·... + logits.

constexpr int Bsz = 2048;
constexpr int Nn  = 784;    // x columns; site n (1..783) uses cores[n-1]
constexpr int NS  = 783;    // mid sites
constexpr int Dd  = 10;

// ---------------- K0: repack weights ----------------
// in : cores[k][i][f][j], f=0 -> A, f=1 -> B   (k*200 + i*20 + f*10 + j)
// out: rw[k][i][0:10] = A_i row, rw[k][i][10:20] = (B_i - A_i) row
__global__ void repack_kernel(const float* __restrict__ cores,
                              float* __restrict__ rw) {
    int tid = blockIdx.x * blockDim.x + threadIdx.x;
    if (tid >= NS * 100) return;
    int k = tid / 100;
    int e = tid - k * 100;
    int i = e / 10, j = e - i * 10;
    const float a  = cores[k * 200 + i * 20 + j];
    const float bb = cores[k * 200 + i * 20 + 10 + j];
    rw[k * 200 + i * 20 + j]      = a;
    rw[k * 200 + i * 20 + 10 + j] = bb - a;
}

// ---------------- K1: per-(sample,chunk) matrix product ----------------
__device__ __forceinline__ void load_blend(const float* __restrict__ wp,
                                           int i, float xv, float mrow[10]) {
    const float4 w0 = *(const float4*)(wp + i * 20 + 0);
    const float4 w1 = *(const float4*)(wp + i * 20 + 4);
    const float4 w2 = *(const float4*)(wp + i * 20 + 8);
    const float4 w3 = *(const float4*)(wp + i * 20 + 12);
    const float4 w4 = *(const float4*)(wp + i * 20 + 16);
    const float va[10] = {w0.x, w0.y, w0.z, w0.w, w1.x, w1.y, w1.z, w1.w, w2.x, w2.y};
    const float vd[10] = {w2.z, w2.w, w3.x, w3.y, w3.z, w3.w, w4.x, w4.y, w4.z, w4.w};
#pragma unroll
    for (int j = 0; j < 10; ++j) mrow[j] = fmaf(xv, vd[j], va[j]);
}

// dst = src * M(site),  M streamed row-by-row (only 10 M-regs live)
__device__ __forceinline__ void site_step(const float* __restrict__ wp, float xv,
                                          const float (&src)[10][10],
                                          float (&dst)[10][10]) {
    float mrow[10];
    load_blend(wp, 0, xv, mrow);
#pragma unroll
    for (int r = 0; r < 10; ++r)
#pragma unroll
        for (int j = 0; j < 10; ++j) dst[r][j] = src[r][0] * mrow[j];
#pragma unroll
    for (int i = 1; i < 10; ++i) {
        load_blend(wp, i, xv, mrow);
#pragma unroll
        for (int r = 0; r < 10; ++r)
#pragma unroll
            for (int j = 0; j < 10; ++j)
                dst[r][j] = fmaf(src[r][i], mrow[j], dst[r][j]);
    }
}

__global__ __launch_bounds__(64, 2) void chunk_kernel(
    const float* __restrict__ x, const float* __restrict__ rw,
    float* __restrict__ pbuf, float* __restrict__ lbuf, int L) {
    const int c = blockIdx.x;
    const int b = blockIdx.y * 64 + (int)threadIdx.x;
    const int n0 = 1 + c * L;
    const int n1 = min(n0 + L, Nn);

    // force weight base into a VGPR so loads stay vector (broadcast) loads and
    // the blend stays a single v_fma per element (no s_load + v_mov pairs)
    uintptr_t wb_u = (uintptr_t)rw;
    asm volatile("" : "+v"(wb_u));
    const float* wbase = (const float*)wb_u;

    const float* __restrict__ xb = x + (size_t)b * Nn;

    float p[10][10], q[10][10];
    int t = n0;
    {   // first site: P = M_{n0}  (saves one matmat per chunk)
        const float xc = xb[t];
        const float* wp = wbase + (size_t)(t - 1) * 200;
        float mrow[10];
#pragma unroll
        for (int i = 0; i < 10; ++i) {
            load_blend(wp, i, xc, mrow);
#pragma unroll
            for (int j = 0; j < 10; ++j) p[i][j] = mrow[j];
        }
    }
    ++t;
    while (t + 1 < n1) {   // ping-pong pairs: p->q->p, no register copies
        const float xa = xb[t];
        const float xc = xb[t + 1];
        site_step(wbase + (size_t)(t - 1) * 200, xa, p, q);
        site_step(wbase + (size_t)t * 200, xc, q, p);
        t += 2;
    }
    if (t < n1) {          // odd tail site
        const float xa = xb[t];
        site_step(wbase + (size_t)(t - 1) * 200, xa, p, q);
#pragma unroll
        for (int r = 0; r < 10; ++r)
#pragma unroll
            for (int j = 0; j < 10; ++j) p[r][j] = q[r][j];
    }

    // Frobenius renorm once per chunk; log factor telescopes into log_norm
    float s = 0.f;
#pragma unroll
    for (int r = 0; r < 10; ++r)
#pragma unroll
        for (int j = 0; j < 10; ++j) s = fmaf(p[r][j], p[r][j], s);
    s = fmaxf(s, 1e-30f);
    const float rin = rsqrtf(s);
    const float lf = 0.5f * __logf(s);

    // store chunk-major-in-b so K2 reads are coalesced
#pragma unroll
    for (int r = 0; r < 10; ++r)
#pragma unroll
        for (int j = 0; j < 10; ++j)
            pbuf[(size_t)(c * 100 + r * 10 + j) * Bsz + b] = p[r][j] * rin;
    lbuf[(size_t)c * Bsz + b] = lf;
}

// ---------------- K2: combine chunks + logits ----------------
__global__ __launch_bounds__(64) void combine_kernel(
    const float* __restrict__ x, const float* __restrict__ core0,
    const float* __restrict__ cls, const float* __restrict__ pbuf,
    const float* __restrict__ lbuf, float* __restrict__ out, int C) {
    const int b = blockIdx.x * 64 + (int)threadIdx.x;

    float v[10];
    const float x0 = x[(size_t)b * Nn];
#pragma unroll
    for (int i = 0; i < 10; ++i) {
        const float c0 = core0[i], c1 = core0[10 + i];
        v[i] = fmaf(x0, c1 - c0, c0);
    }

    float llog = 0.f;
    for (int c = 0; c < C; ++c) {
        float nv[10];
#pragma unroll
        for (int j = 0; j < 10; ++j) nv[j] = 0.f;
#pragma unroll
        for (int i = 0; i < 10; ++i)
#pragma unroll
            for (int j = 0; j < 10; ++j)
                nv[j] = fmaf(v[i],
                             pbuf[(size_t)(c * 100 + i * 10 + j) * Bsz + b],
                             nv[j]);
        llog += lbuf[(size_t)c * Bsz + b];
        float s = 0.f;
#pragma unroll
        for (int j = 0; j < 10; ++j) s = fmaf(nv[j], nv[j], s);
        s = fmaxf(s, 1e-30f);
        const float rin = rsqrtf(s);
        llog += 0.5f * __logf(s);
#pragma unroll
        for (int j = 0; j < 10; ++j) v[j] = nv[j] * rin;
    }

#pragma unroll
    for (int o = 0; o < 10; ++o) {
        float acc = llog;
#pragma unroll
        for (int i = 0; i < 10; ++i) acc = fmaf(v[i], cls[o * 10 + i], acc);
        out[(size_t)b * 10 + o] = acc;
    }
}

// ---------------- launch ----------------
extern "C" void kernel_launch(void* const* d_in, const int* in_sizes, int n_in,
                              void* d_out, int out_size, void* d_ws, size_t ws_size,
                              hipStream_t stream) {
    const float* x     = (const float*)d_in[0];
    const float* core0 = (const float*)d_in[1];
    const float* cores = (const float*)d_in[2];
    const float* cls   = (const float*)d_in[3];
    float* out = (float*)d_out;

    float* rw = (float*)d_ws;                       // NS*200 floats = 626400 B
    size_t off = ((size_t)NS * 200 * 4 + 255) & ~(size_t)255;
    size_t per_chunk = (size_t)100 * Bsz * 4 + (size_t)Bsz * 4;  // P + log
    size_t avail = ws_size > off ? ws_size - off : 0;
    int C = (int)(avail / per_chunk);
    if (C > 61) C = 61;
    if (C < 1)  C = 1;
    int L = (NS + C - 1) / C;
    C = (NS + L - 1) / L;                           // tighten
    float* pbuf = (float*)((char*)d_ws + off);
    float* lbuf = pbuf + (size_t)C * 100 * Bsz;

    hipLaunchKernelGGL(repack_kernel, dim3((NS * 100 + 255) / 256), dim3(256),
                       0, stream, cores, rw);
    hipLaunchKernelGGL(chunk_kernel, dim3(C, Bsz / 64), dim3(64),
                       0, stream, x, rw, pbuf, lbuf, L);
    hipLaunchKernelGGL(combine_kernel, dim3(Bsz / 64), dim3(64),
                       0, stream, x, core0, cls, pbuf, lbuf, out, C);
}

// Round 3
// 204.882 us; speedup vs baseline: 2.5842x; 2.5842x over previous
//
#include <hip/hip_runtime.h>

// MPS classifier: logits[b,o] = (v/||v||)·cls[o] + log||v||,
//   v = head0(b) · M_1(b) · ... · M_783(b),  M_n = A_n + x[b,n]*(B_n - A_n).
// Chain is associative; all normalizations telescope, so:
//   K0: repack cores -> per-site rows of interleaved {A, B-A} pairs
//   K1: each PAIR of lanes computes the 10x10 product of one (sample, chunk):
//       lane h in {0,1} owns rows 5h..5h+4 (50 regs) + dst (50) + mrow (10)
//       => ~125 VGPRs, NO spill (round-2's full-matrix version spilled).
//   K2: per-sample sequential combine over chunks + logits (16 lanes/sample).

constexpr int Bsz = 2048;
constexpr int Nn  = 784;    // x columns; site n (1..783) uses cores[n-1]
constexpr int NS  = 783;    // mid sites

// ---------------- K0: repack weights ----------------
// in : cores[k][i][f][j]  (k*200 + i*20 + f*10 + j), f=0 -> A, f=1 -> B
// out: rw[k][i][2j] = A[i][j], rw[k][i][2j+1] = B[i][j]-A[i][j]
__global__ void repack_kernel(const float* __restrict__ cores,
                              float* __restrict__ rw) {
    int tid = blockIdx.x * blockDim.x + threadIdx.x;
    if (tid >= NS * 100) return;
    int k = tid / 100;
    int e = tid - k * 100;
    int i = e / 10, j = e - i * 10;
    const float a  = cores[k * 200 + i * 20 + j];
    const float bb = cores[k * 200 + i * 20 + 10 + j];
    rw[k * 200 + i * 20 + 2 * j]     = a;
    rw[k * 200 + i * 20 + 2 * j + 1] = bb - a;
}

// ---------------- K1 helpers ----------------
// one weight row: 10 pairs {A, D}; each float4 -> 2 blended outputs
__device__ __forceinline__ void load_blend(const float* __restrict__ wrow,
                                           float xv, float (&m)[10]) {
#pragma unroll
    for (int q = 0; q < 5; ++q) {
        const float4 w = *(const float4*)(wrow + q * 4);
        m[2 * q]     = fmaf(xv, w.y, w.x);
        m[2 * q + 1] = fmaf(xv, w.w, w.z);
    }
}

// dst(5x10) = src(5x10) * M(site), M streamed row-by-row
__device__ __forceinline__ void site_step(const float* __restrict__ wp, float xv,
                                          const float (&src)[5][10],
                                          float (&dst)[5][10]) {
    float m[10];
    load_blend(wp, xv, m);
#pragma unroll
    for (int r = 0; r < 5; ++r)
#pragma unroll
        for (int j = 0; j < 10; ++j) dst[r][j] = src[r][0] * m[j];
#pragma unroll
    for (int i = 1; i < 10; ++i) {
        load_blend(wp + i * 20, xv, m);
#pragma unroll
        for (int r = 0; r < 5; ++r)
#pragma unroll
            for (int j = 0; j < 10; ++j)
                dst[r][j] = fmaf(src[r][i], m[j], dst[r][j]);
    }
}

// ---------------- K1: per-(sample,chunk) product, 2 lanes per unit ----------
__global__ __launch_bounds__(256) void chunk_kernel(
    const float* __restrict__ x, const float* __restrict__ rw,
    float* __restrict__ pbuf, float* __restrict__ lbuf, int L) {
    const int c = blockIdx.x;
    const int h = (int)threadIdx.x & 1;                 // row-half owner
    const int b = blockIdx.y * 128 + ((int)threadIdx.x >> 1);
    const int n0 = 1 + c * L;
    const int n1 = min(n0 + L, Nn);

    // keep the (block-uniform) weight base in a VGPR so weight reads stay
    // vector broadcast loads and the blend is 1 v_fma per element
    uintptr_t wb_u = (uintptr_t)(rw + (size_t)(n0 - 1) * 200);
    asm volatile("" : "+v"(wb_u));
    const float* wp = (const float*)wb_u;

    const float* __restrict__ xb = x + (size_t)b * Nn;

    float p[5][10], q[5][10];
    {   // first site: P = M  (own rows 5h..5h+4)
        const float xv = xb[n0];
        float m[10];
#pragma unroll
        for (int r = 0; r < 5; ++r) {
            load_blend(wp + (5 * h + r) * 20, xv, m);
#pragma unroll
            for (int j = 0; j < 10; ++j) p[r][j] = m[j];
        }
    }
    int t = n0 + 1;
    wp += 200;
    while (t + 1 < n1) {          // ping-pong pairs, no copies
        site_step(wp,        xb[t],     p, q);
        site_step(wp + 200,  xb[t + 1], q, p);
        wp += 400;
        t  += 2;
    }
    if (t < n1) {                 // odd tail (not hit for odd L, kept for safety)
        site_step(wp, xb[t], p, q);
#pragma unroll
        for (int r = 0; r < 5; ++r)
#pragma unroll
            for (int j = 0; j < 10; ++j) p[r][j] = q[r][j];
    }

    // Frobenius renorm once per chunk (both halves via shfl_xor)
    float s = 0.f;
#pragma unroll
    for (int r = 0; r < 5; ++r)
#pragma unroll
        for (int j = 0; j < 10; ++j) s = fmaf(p[r][j], p[r][j], s);
    s += __shfl_xor(s, 1);
    s = fmaxf(s, 1e-30f);
    const float rin = rsqrtf(s);
    if (h == 0) lbuf[(size_t)c * Bsz + b] = 0.5f * __logf(s);

    // store chunk-major-in-b so K2 reads are coalesced
#pragma unroll
    for (int r = 0; r < 5; ++r)
#pragma unroll
        for (int j = 0; j < 10; ++j)
            pbuf[(size_t)(c * 100 + (5 * h + r) * 10 + j) * Bsz + b] =
                p[r][j] * rin;
}

// ---------------- K2: combine chunks + logits (16 lanes per sample) --------
__global__ __launch_bounds__(256) void combine_kernel(
    const float* __restrict__ x, const float* __restrict__ core0,
    const float* __restrict__ cls, const float* __restrict__ pbuf,
    const float* __restrict__ lbuf, float* __restrict__ out, int C) {
    const int j     = (int)threadIdx.x & 15;
    const int jj    = (j < 10) ? j : 9;                 // clamp idle lanes' addr
    const int gbase = (int)threadIdx.x & 48;            // 16-group base in wave
    const int b     = blockIdx.x * 16 + ((int)threadIdx.x >> 4);

    float v[10];
    const float x0 = x[(size_t)b * Nn];
#pragma unroll
    for (int i = 0; i < 10; ++i) {
        const float c0 = core0[i], c1 = core0[10 + i];
        v[i] = fmaf(x0, c1 - c0, c0);
    }

    float llog = 0.f;
    for (int c = 0; c < C; ++c) {
        const float* __restrict__ pc =
            pbuf + (size_t)(c * 100 + jj) * Bsz + b;
        float acc = 0.f;
#pragma unroll
        for (int i = 0; i < 10; ++i)
            acc = fmaf(v[i], pc[(size_t)(i * 10) * Bsz], acc);
        if (j >= 10) acc = 0.f;
        float s = acc * acc;
        s += __shfl_xor(s, 1);
        s += __shfl_xor(s, 2);
        s += __shfl_xor(s, 4);
        s += __shfl_xor(s, 8);
        s = fmaxf(s, 1e-30f);
        const float rin = rsqrtf(s);
        llog += lbuf[(size_t)c * Bsz + b] + 0.5f * __logf(s);
        const float nvn = acc * rin;
#pragma unroll
        for (int i = 0; i < 10; ++i) v[i] = __shfl(nvn, gbase + i);
    }

    if (j < 10) {
        float acc = llog;
#pragma unroll
        for (int i = 0; i < 10; ++i) acc = fmaf(v[i], cls[j * 10 + i], acc);
        out[(size_t)b * 10 + j] = acc;
    }
}

// ---------------- launch ----------------
extern "C" void kernel_launch(void* const* d_in, const int* in_sizes, int n_in,
                              void* d_out, int out_size, void* d_ws, size_t ws_size,
                              hipStream_t stream) {
    const float* x     = (const float*)d_in[0];
    const float* core0 = (const float*)d_in[1];
    const float* cores = (const float*)d_in[2];
    const float* cls   = (const float*)d_in[3];
    float* out = (float*)d_out;

    float* rw = (float*)d_ws;                       // NS*200 floats
    size_t off = ((size_t)NS * 200 * 4 + 255) & ~(size_t)255;
    size_t per_chunk = (size_t)100 * Bsz * 4 + (size_t)Bsz * 4;  // P + log
    size_t avail = ws_size > off ? ws_size - off : 0;
    int C = (int)(avail / per_chunk);
    if (C > 61) C = 61;
    if (C < 1)  C = 1;
    int L = (NS + C - 1) / C;
    C = (NS + L - 1) / L;                           // tighten
    float* pbuf = (float*)((char*)d_ws + off);
    float* lbuf = pbuf + (size_t)C * 100 * Bsz;

    hipLaunchKernelGGL(repack_kernel, dim3((NS * 100 + 255) / 256), dim3(256),
                       0, stream, cores, rw);
    hipLaunchKernelGGL(chunk_kernel, dim3(C, Bsz / 128), dim3(256),
                       0, stream, x, rw, pbuf, lbuf, L);
    hipLaunchKernelGGL(combine_kernel, dim3(Bsz / 16), dim3(256),
                       0, stream, x, core0, cls, pbuf, lbuf, out, C);
}

// Round 4
// 127.894 us; speedup vs baseline: 4.1398x; 1.6020x over previous
//
#include <hip/hip_runtime.h>

// MPS classifier: logits[b,o] = (v/||v||)·cls[o] + log||v||,
//   v = head0(b) · M_1(b) · ... · M_783(b),  M_n = A_n + x[b,n]*(B_n - A_n).
// Chain is associative; normalizations telescope.
//   K0: repack cores -> per-site rows of interleaved {A, B-A} pairs
//   K1: per (sample, chunk): 2 lanes own 5 rows each of the running 10x10
//       product, entirely in registers. Weights + x staged in LDS per block
//       (wave-uniform broadcast ds_read_b128, no L1 thrash).
//   K2: per-sample sequential combine over chunks, software-pipelined
//       (prefetch next chunk's P-column before the serial norm chain).

constexpr int Bsz  = 2048;
constexpr int Nn   = 784;    // x columns; site n (1..783) uses cores[n-1]
constexpr int NS   = 783;    // mid sites
constexpr int MAXL = 16;     // max sites per chunk the LDS buffer supports

// ---------------- K0: repack weights ----------------
// in : cores[k][i][f][j]  (k*200 + i*20 + f*10 + j), f=0 -> A, f=1 -> B
// out: rw[k][i][2j] = A[i][j], rw[k][i][2j+1] = B[i][j]-A[i][j]
__global__ void repack_kernel(const float* __restrict__ cores,
                              float* __restrict__ rw) {
    int tid = blockIdx.x * blockDim.x + threadIdx.x;
    if (tid >= NS * 100) return;
    int k = tid / 100;
    int e = tid - k * 100;
    int i = e / 10, j = e - i * 10;
    const float a  = cores[k * 200 + i * 20 + j];
    const float bb = cores[k * 200 + i * 20 + 10 + j];
    rw[k * 200 + i * 20 + 2 * j]     = a;
    rw[k * 200 + i * 20 + 2 * j + 1] = bb - a;
}

// ---------------- K1 helpers ----------------
// one weight row: 10 pairs {A, D}; each float4 -> 2 blended outputs
__device__ __forceinline__ void load_blend(const float* __restrict__ wrow,
                                           float xv, float (&m)[10]) {
#pragma unroll
    for (int q = 0; q < 5; ++q) {
        const float4 w = *(const float4*)(wrow + q * 4);
        m[2 * q]     = fmaf(xv, w.y, w.x);
        m[2 * q + 1] = fmaf(xv, w.w, w.z);
    }
}

// dst(5x10) = src(5x10) * M(site), M streamed row-by-row from LDS
__device__ __forceinline__ void site_step(const float* __restrict__ wp, float xv,
                                          const float (&src)[5][10],
                                          float (&dst)[5][10]) {
    float m[10];
    load_blend(wp, xv, m);
#pragma unroll
    for (int r = 0; r < 5; ++r)
#pragma unroll
        for (int j = 0; j < 10; ++j) dst[r][j] = src[r][0] * m[j];
#pragma unroll
    for (int i = 1; i < 10; ++i) {
        load_blend(wp + i * 20, xv, m);
#pragma unroll
        for (int r = 0; r < 5; ++r)
#pragma unroll
            for (int j = 0; j < 10; ++j)
                dst[r][j] = fmaf(src[r][i], m[j], dst[r][j]);
    }
}

// ---------------- K1: per-(sample,chunk) product, 2 lanes per unit ----------
__global__ __launch_bounds__(256) void chunk_kernel(
    const float* __restrict__ x, const float* __restrict__ rw,
    float* __restrict__ pbuf, float* __restrict__ lbuf, int L) {
    __shared__ float s_w[MAXL * 200];   // chunk weights, {A,D} interleaved
    __shared__ float s_x[128 * 17];     // x slice, stride 17 = conflict-free

    const int c   = blockIdx.x;
    const int n0  = 1 + c * L;
    const int n1  = min(n0 + L, Nn);
    const int ns  = n1 - n0;            // sites in this chunk (>=1)
    const int tid = (int)threadIdx.x;
    const int b0  = (int)blockIdx.y * 128;

    // stage weights: ns*200 floats = ns*50 float4, coalesced
    const float4* gw = (const float4*)(rw + (size_t)(n0 - 1) * 200);
    for (int idx = tid; idx < ns * 50; idx += 256)
        ((float4*)s_w)[idx] = gw[idx];
    // stage x slice: e = k*128 + bl
    for (int e = tid; e < ns * 128; e += 256) {
        int k = e >> 7, bl = e & 127;
        s_x[bl * 17 + k] = x[(size_t)(b0 + bl) * Nn + n0 + k];
    }
    __syncthreads();

    const int h = tid & 1;              // row-half owner
    const int u = tid >> 1;             // sample slot 0..127
    const int b = b0 + u;
    const float* __restrict__ xs = s_x + u * 17;

    float p[5][10], q[5][10];
    {   // first site: P = M (rows 5h..5h+4)
        const float xv = xs[0];
        float m[10];
#pragma unroll
        for (int r = 0; r < 5; ++r) {
            load_blend(s_w + (5 * h + r) * 20, xv, m);
#pragma unroll
            for (int j = 0; j < 10; ++j) p[r][j] = m[j];
        }
    }
    int k = 1;
    const float* wp = s_w + 200;
    while (k + 1 < ns) {                // ping-pong pairs, no copies
        site_step(wp,       xs[k],     p, q);
        site_step(wp + 200, xs[k + 1], q, p);
        wp += 400;
        k  += 2;
    }
    if (k < ns) {                       // odd tail
        site_step(wp, xs[k], p, q);
#pragma unroll
        for (int r = 0; r < 5; ++r)
#pragma unroll
            for (int j = 0; j < 10; ++j) p[r][j] = q[r][j];
    }

    // Frobenius renorm once per chunk (both halves via shfl_xor)
    float s = 0.f;
#pragma unroll
    for (int r = 0; r < 5; ++r)
#pragma unroll
        for (int j = 0; j < 10; ++j) s = fmaf(p[r][j], p[r][j], s);
    s += __shfl_xor(s, 1);
    s = fmaxf(s, 1e-30f);
    const float rin = rsqrtf(s);
    if (h == 0) lbuf[(size_t)c * Bsz + b] = 0.5f * __logf(s);

    // store chunk-major-in-b so K2 reads are coalesced
#pragma unroll
    for (int r = 0; r < 5; ++r)
#pragma unroll
        for (int j = 0; j < 10; ++j)
            pbuf[(size_t)(c * 100 + (5 * h + r) * 10 + j) * Bsz + b] =
                p[r][j] * rin;
}

// ---------------- K2: combine chunks + logits (16 lanes per sample) --------
// software-pipelined: chunk c+1's P-column loads issue before chunk c's
// serial norm/shuffle chain, hiding L2 latency.
__global__ __launch_bounds__(256) void combine_kernel(
    const float* __restrict__ x, const float* __restrict__ core0,
    const float* __restrict__ cls, const float* __restrict__ pbuf,
    const float* __restrict__ lbuf, float* __restrict__ out, int C) {
    const int tid   = (int)threadIdx.x;
    const int j     = tid & 15;
    const int jj    = (j < 10) ? j : 9;      // clamp idle lanes' addr
    const int gbase = tid & 48;              // 16-group base within wave
    const int b     = blockIdx.x * 16 + (tid >> 4);

    float v[10];
    const float x0 = x[(size_t)b * Nn];
#pragma unroll
    for (int i = 0; i < 10; ++i) {
        const float c0 = core0[i], c1 = core0[10 + i];
        v[i] = fmaf(x0, c1 - c0, c0);
    }

    float w[10];
    {
        const float* p0 = pbuf + (size_t)jj * Bsz + b;
#pragma unroll
        for (int i = 0; i < 10; ++i) w[i] = p0[(size_t)(i * 10) * Bsz];
    }

    float llog = 0.f;
    for (int c = 0; c < C; ++c) {
        float wn[10];
        if (c + 1 < C) {
            const float* pn = pbuf + (size_t)((c + 1) * 100 + jj) * Bsz + b;
#pragma unroll
            for (int i = 0; i < 10; ++i) wn[i] = pn[(size_t)(i * 10) * Bsz];
        } else {
#pragma unroll
            for (int i = 0; i < 10; ++i) wn[i] = 0.f;
        }
        float acc = 0.f;
#pragma unroll
        for (int i = 0; i < 10; ++i) acc = fmaf(v[i], w[i], acc);
        if (j >= 10) acc = 0.f;
        float s = acc * acc;
        s += __shfl_xor(s, 1);
        s += __shfl_xor(s, 2);
        s += __shfl_xor(s, 4);
        s += __shfl_xor(s, 8);
        s = fmaxf(s, 1e-30f);
        const float rin = rsqrtf(s);
        llog += lbuf[(size_t)c * Bsz + b] + 0.5f * __logf(s);
        const float nvn = acc * rin;
#pragma unroll
        for (int i = 0; i < 10; ++i) v[i] = __shfl(nvn, gbase + i);
#pragma unroll
        for (int i = 0; i < 10; ++i) w[i] = wn[i];
    }

    if (j < 10) {
        float acc = llog;
#pragma unroll
        for (int i = 0; i < 10; ++i) acc = fmaf(v[i], cls[j * 10 + i], acc);
        out[(size_t)b * 10 + j] = acc;
    }
}

// ---------------- launch ----------------
extern "C" void kernel_launch(void* const* d_in, const int* in_sizes, int n_in,
                              void* d_out, int out_size, void* d_ws, size_t ws_size,
                              hipStream_t stream) {
    const float* x     = (const float*)d_in[0];
    const float* core0 = (const float*)d_in[1];
    const float* cores = (const float*)d_in[2];
    const float* cls   = (const float*)d_in[3];
    float* out = (float*)d_out;

    float* rw = (float*)d_ws;                       // NS*200 floats
    size_t off = ((size_t)NS * 200 * 4 + 255) & ~(size_t)255;
    size_t per_chunk = (size_t)100 * Bsz * 4 + (size_t)Bsz * 4;  // P + log
    size_t avail = ws_size > off ? ws_size - off : 0;
    int C = (int)(avail / per_chunk);
    if (C > 61) C = 61;
    if (C < 1)  C = 1;
    int L = (NS + C - 1) / C;
    C = (NS + L - 1) / L;                           // tighten
    float* pbuf = (float*)((char*)d_ws + off);
    float* lbuf = pbuf + (size_t)C * 100 * Bsz;

    hipLaunchKernelGGL(repack_kernel, dim3((NS * 100 + 255) / 256), dim3(256),
                       0, stream, cores, rw);
    hipLaunchKernelGGL(chunk_kernel, dim3(C, Bsz / 128), dim3(256),
                       0, stream, x, rw, pbuf, lbuf, L);
    hipLaunchKernelGGL(combine_kernel, dim3(Bsz / 16), dim3(256),
                       0, stream, x, core0, cls, pbuf, lbuf, out, C);
}